// Round 1
// baseline (473.348 us; speedup 1.0000x reference)
//
#include <hip/hip_runtime.h>
#include <math.h>

#define N_NODES 50000
#define N_EDGES 800000
#define E_TOTAL (N_NODES + N_EDGES)
#define IN_F 256
#define OUT_F 128
#define ALPHA 0.2f

#define ROWS_PER_WAVE 8
#define GEMM_WAVES (N_NODES / ROWS_PER_WAVE)   // 6250, exact (50000 % 8 == 0)

// ---------------- K0: init counters/accumulators ----------------
__global__ __launch_bounds__(256) void k_init(float* denom, int* cnt, int* total) {
    int i = blockIdx.x * blockDim.x + threadIdx.x;
    if (i < N_NODES) { denom[i] = 0.0f; cnt[i] = 0; }
    if (i == 0) *total = 0;
}

// ---------------- K1: Wh = h @ W  (f32 vector GEMM) ----------------
// One wave computes 8 rows x 128 cols. Each lane owns 2 consecutive cols
// (float2). W row slice is loaded once per k and reused across 8 rows.
__global__ __launch_bounds__(256) void k_gemm(const float* __restrict__ h,
                                              const float* __restrict__ W,
                                              float* __restrict__ Wh) {
    int wave = (blockIdx.x * blockDim.x + threadIdx.x) >> 6;
    int lane = threadIdx.x & 63;
    if (wave >= GEMM_WAVES) return;
    int row0 = wave * ROWS_PER_WAVE;

    float2 acc[ROWS_PER_WAVE];
#pragma unroll
    for (int r = 0; r < ROWS_PER_WAVE; ++r) acc[r] = make_float2(0.0f, 0.0f);

    const float2* __restrict__ Wv = (const float2*)W;  // [IN_F][OUT_F/2]
    const float* __restrict__ h0 = h + (size_t)row0 * IN_F;

#pragma unroll 4
    for (int k = 0; k < IN_F; ++k) {
        float2 w = Wv[k * (OUT_F / 2) + lane];
#pragma unroll
        for (int r = 0; r < ROWS_PER_WAVE; ++r) {
            float hv = h0[r * IN_F + k];   // wave-uniform -> scalar load
            acc[r].x = fmaf(hv, w.x, acc[r].x);
            acc[r].y = fmaf(hv, w.y, acc[r].y);
        }
    }

    float2* __restrict__ Whv = (float2*)Wh;  // [N][OUT_F/2]
#pragma unroll
    for (int r = 0; r < ROWS_PER_WAVE; ++r)
        Whv[(size_t)(row0 + r) * (OUT_F / 2) + lane] = acc[r];
}

// ---------------- K2: per-node attention scores ----------------
// One wave per node: s_src = Wh_row . a[:128], s_dst = Wh_row . a[128:]
__global__ __launch_bounds__(256) void k_scores(const float* __restrict__ Wh,
                                                const float* __restrict__ a,
                                                float* __restrict__ s_src,
                                                float* __restrict__ s_dst) {
    int wave = (blockIdx.x * blockDim.x + threadIdx.x) >> 6;
    int lane = threadIdx.x & 63;
    if (wave >= N_NODES) return;
    float2 v  = ((const float2*)(Wh + (size_t)wave * OUT_F))[lane];
    float2 a1 = ((const float2*)a)[lane];
    float2 a2 = ((const float2*)(a + OUT_F))[lane];
    float s1 = v.x * a1.x + v.y * a1.y;
    float s2 = v.x * a2.x + v.y * a2.y;
#pragma unroll
    for (int off = 32; off > 0; off >>= 1) {
        s1 += __shfl_down(s1, off);
        s2 += __shfl_down(s2, off);
    }
    if (lane == 0) { s_src[wave] = s1; s_dst[wave] = s2; }
}

// ---------------- K3: count in-degree per destination ----------------
__global__ __launch_bounds__(256) void k_count(const int* __restrict__ adj,
                                               int* __restrict__ cnt) {
    int e = blockIdx.x * blockDim.x + threadIdx.x;
    if (e >= E_TOTAL) return;
    int col = (e < N_EDGES) ? adj[N_EDGES + e] : (e - N_EDGES);
    atomicAdd(&cnt[col], 1);
}

// ---------------- K4: segment offsets (order-free exclusive scan) ----------------
__global__ __launch_bounds__(256) void k_offsets(const int* __restrict__ cnt,
                                                 int* __restrict__ start,
                                                 int* __restrict__ fillptr,
                                                 int* total) {
    int i = blockIdx.x * blockDim.x + threadIdx.x;
    if (i >= N_NODES) return;
    int s = atomicAdd(total, cnt[i]);
    start[i] = s;
    fillptr[i] = s;
}

// ---------------- K5: fill CSR, compute exp(leakyrelu), accumulate denom ----
__global__ __launch_bounds__(256) void k_fill(const int* __restrict__ adj,
                                              const float* __restrict__ s_src,
                                              const float* __restrict__ s_dst,
                                              int* __restrict__ fillptr,
                                              float* __restrict__ denom,
                                              int* __restrict__ srcidx,
                                              float* __restrict__ exv) {
    int e = blockIdx.x * blockDim.x + threadIdx.x;
    if (e >= E_TOTAL) return;
    int row, col;
    if (e < N_EDGES) { row = adj[e]; col = adj[N_EDGES + e]; }
    else             { row = col = e - N_EDGES; }
    float s = s_dst[col] + s_src[row];
    float lr = (s > 0.0f) ? s : ALPHA * s;
    float ex = expf(lr);   // no max-shift needed: |s| << 88 by construction
    int pos = atomicAdd(&fillptr[col], 1);
    srcidx[pos] = row;
    exv[pos] = ex;
    atomicAdd(&denom[col], ex);
}

// ---------------- K6: gather, normalize, ELU ----------------
// One wave per destination node; lane owns 2 consecutive features.
__global__ __launch_bounds__(256) void k_gather(const float* __restrict__ Wh,
                                                const int* __restrict__ start,
                                                const int* __restrict__ cnt,
                                                const int* __restrict__ srcidx,
                                                const float* __restrict__ exv,
                                                const float* __restrict__ denom,
                                                float* __restrict__ out) {
    int wave = (blockIdx.x * blockDim.x + threadIdx.x) >> 6;
    int lane = threadIdx.x & 63;
    if (wave >= N_NODES) return;
    int s0 = start[wave];
    int n  = cnt[wave];
    const float2* __restrict__ Wv = (const float2*)Wh;
    float2 acc = make_float2(0.0f, 0.0f);
    for (int j = 0; j < n; ++j) {
        int   r = srcidx[s0 + j];   // wave-uniform
        float x = exv[s0 + j];      // wave-uniform
        float2 w = Wv[(size_t)r * (OUT_F / 2) + lane];
        acc.x = fmaf(x, w.x, acc.x);
        acc.y = fmaf(x, w.y, acc.y);
    }
    float inv = 1.0f / denom[wave];
    float vx = acc.x * inv;
    float vy = acc.y * inv;
    vx = (vx > 0.0f) ? vx : expm1f(vx);
    vy = (vy > 0.0f) ? vy : expm1f(vy);
    ((float2*)(out + (size_t)wave * OUT_F))[lane] = make_float2(vx, vy);
}

// ---------------- launcher ----------------
extern "C" void kernel_launch(void* const* d_in, const int* in_sizes, int n_in,
                              void* d_out, int out_size, void* d_ws, size_t ws_size,
                              hipStream_t stream) {
    const float* h   = (const float*)d_in[0];
    const int*   adj = (const int*)d_in[1];
    const float* W   = (const float*)d_in[2];
    const float* a   = (const float*)d_in[3];
    float* out = (float*)d_out;

    // workspace layout (256B-aligned chunks)
    char* ws = (char*)d_ws;
    const size_t SZ_WH  = (size_t)N_NODES * OUT_F * 4;   // 25,600,000 (mult of 256)
    const size_t SZ_N   = 200704;                        // >= N_NODES*4, 256-aligned
    const size_t SZ_E   = 3400192;                       // >= E_TOTAL*4, 256-aligned
    float* Wh      = (float*)(ws);
    float* s_src   = (float*)(ws + SZ_WH);
    float* s_dst   = (float*)(ws + SZ_WH + SZ_N);
    float* denom   = (float*)(ws + SZ_WH + 2 * SZ_N);
    int*   cnt     = (int*)  (ws + SZ_WH + 3 * SZ_N);
    int*   start   = (int*)  (ws + SZ_WH + 4 * SZ_N);
    int*   fillptr = (int*)  (ws + SZ_WH + 5 * SZ_N);
    int*   total   = (int*)  (ws + SZ_WH + 6 * SZ_N);
    int*   srcidx  = (int*)  (ws + SZ_WH + 6 * SZ_N + 256);
    float* exv     = (float*)(ws + SZ_WH + 6 * SZ_N + 256 + SZ_E);

    (void)in_sizes; (void)n_in; (void)out_size; (void)ws_size;

    const int B = 256;
    k_init   <<<(N_NODES + B - 1) / B, B, 0, stream>>>(denom, cnt, total);
    k_gemm   <<<(GEMM_WAVES * 64 + B - 1) / B, B, 0, stream>>>(h, W, Wh);
    k_scores <<<(N_NODES * 64 + B - 1) / B, B, 0, stream>>>(Wh, a, s_src, s_dst);
    k_count  <<<(E_TOTAL + B - 1) / B, B, 0, stream>>>(adj, cnt);
    k_offsets<<<(N_NODES + B - 1) / B, B, 0, stream>>>(cnt, start, fillptr, total);
    k_fill   <<<(E_TOTAL + B - 1) / B, B, 0, stream>>>(adj, s_src, s_dst, fillptr,
                                                       denom, srcidx, exv);
    k_gather <<<(N_NODES * 64 + B - 1) / B, B, 0, stream>>>(Wh, start, cnt, srcidx,
                                                            exv, denom, out);
}

// Round 2
// 355.088 us; speedup vs baseline: 1.3330x; 1.3330x over previous
//
#include <hip/hip_runtime.h>
#include <math.h>

#define N_NODES 50000
#define N_EDGES 800000
#define E_TOTAL (N_NODES + N_EDGES)
#define IN_F 256
#define OUT_F 128
#define ALPHA 0.2f

#define TILE_M 64
#define BK 8
#define KTILES (IN_F / BK)          // 32
#define GEMM_BLOCKS ((N_NODES + TILE_M - 1) / TILE_M)   // 782

// ---------------- K0: init counters/accumulators ----------------
__global__ __launch_bounds__(256) void k_init(float* denom, int* cnt, int* total) {
    int i = blockIdx.x * blockDim.x + threadIdx.x;
    if (i < N_NODES) { denom[i] = 0.0f; cnt[i] = 1; }  // 1 = implicit self-loop
    if (i == 0) *total = 0;
}

// ---------------- K1: Wh = h @ W  (LDS-tiled f32 GEMM) + fused scores -------
// 128 threads/block, 64 rows x 128 cols per block. Thread (tx=t&15, ty=t>>4)
// computes an 8x8 register tile: rows ty*8.., cols tx*8... BK=8 k-slab staged
// in LDS; next slab register-prefetched during compute.
// Epilogue fuses s_src = Wh.a1, s_dst = Wh.a2 (width-16 shfl_xor reduction).
__global__ __launch_bounds__(128) void k_gemm(const float* __restrict__ h,
                                              const float* __restrict__ W,
                                              const float* __restrict__ a,
                                              float* __restrict__ Wh,
                                              float* __restrict__ s_src,
                                              float* __restrict__ s_dst) {
    __shared__ float hs[BK][TILE_M];       // k-major (transposed) h slab
    __shared__ float ws[BK][OUT_F + 4];    // +4 pad

    const int t = threadIdx.x;
    const int row0 = blockIdx.x * TILE_M;
    const int tx = t & 15, ty = t >> 4;

    // --- staging thread mapping ---
    const int lrow = t >> 1;               // 0..63 (h tile row)
    const int lk   = (t & 1) * 4;          // 0 or 4 (k sub-offset)
    int hrow = row0 + lrow; if (hrow >= N_NODES) hrow = N_NODES - 1;  // clamp; stores guarded
    const float* __restrict__ hp = h + (size_t)hrow * IN_F + lk;
    const int wrow = t >> 4;               // 0..7 (k within slab)
    const int wcol = (t & 15) * 8;
    const float* __restrict__ wp = W + (size_t)wrow * OUT_F + wcol;

    float acc[8][8];
#pragma unroll
    for (int r = 0; r < 8; ++r)
#pragma unroll
        for (int c = 0; c < 8; ++c) acc[r][c] = 0.0f;

    // --- prologue: stage slab 0 ---
    {
        float4 hv  = *(const float4*)hp;
        float4 wv0 = *(const float4*)wp;
        float4 wv1 = *(const float4*)(wp + 4);
        hs[lk + 0][lrow] = hv.x; hs[lk + 1][lrow] = hv.y;
        hs[lk + 2][lrow] = hv.z; hs[lk + 3][lrow] = hv.w;
        *(float4*)&ws[wrow][wcol]     = wv0;
        *(float4*)&ws[wrow][wcol + 4] = wv1;
    }
    __syncthreads();

    for (int kt = 0; kt < KTILES; ++kt) {
        // register-prefetch next slab (overlaps with compute below)
        float4 nhv, nwv0, nwv1;
        const bool more = (kt + 1 < KTILES);
        if (more) {
            const float* hp2 = hp + (kt + 1) * BK;
            nhv = *(const float4*)hp2;
            const float* wp2 = wp + (size_t)(kt + 1) * BK * OUT_F;
            nwv0 = *(const float4*)wp2;
            nwv1 = *(const float4*)(wp2 + 4);
        }
#pragma unroll
        for (int kk = 0; kk < BK; ++kk) {
            float4 hA = *(const float4*)&hs[kk][ty * 8];
            float4 hB = *(const float4*)&hs[kk][ty * 8 + 4];
            float4 wA = *(const float4*)&ws[kk][tx * 8];
            float4 wB = *(const float4*)&ws[kk][tx * 8 + 4];
            float hr[8] = {hA.x, hA.y, hA.z, hA.w, hB.x, hB.y, hB.z, hB.w};
            float wc[8] = {wA.x, wA.y, wA.z, wA.w, wB.x, wB.y, wB.z, wB.w};
#pragma unroll
            for (int r = 0; r < 8; ++r)
#pragma unroll
                for (int c = 0; c < 8; ++c)
                    acc[r][c] = fmaf(hr[r], wc[c], acc[r][c]);
        }
        if (more) {
            __syncthreads();
            hs[lk + 0][lrow] = nhv.x; hs[lk + 1][lrow] = nhv.y;
            hs[lk + 2][lrow] = nhv.z; hs[lk + 3][lrow] = nhv.w;
            *(float4*)&ws[wrow][wcol]     = nwv0;
            *(float4*)&ws[wrow][wcol + 4] = nwv1;
            __syncthreads();
        }
    }

    // --- epilogue: store Wh, fused attention scores ---
    float a1[8], a2[8];
    *(float4*)&a1[0] = *(const float4*)(a + tx * 8);
    *(float4*)&a1[4] = *(const float4*)(a + tx * 8 + 4);
    *(float4*)&a2[0] = *(const float4*)(a + OUT_F + tx * 8);
    *(float4*)&a2[4] = *(const float4*)(a + OUT_F + tx * 8 + 4);

#pragma unroll
    for (int r = 0; r < 8; ++r) {
        const int grow = row0 + ty * 8 + r;
        const bool valid = (grow < N_NODES);
        if (valid) {
            float* o = Wh + (size_t)grow * OUT_F + tx * 8;
            *(float4*)o       = make_float4(acc[r][0], acc[r][1], acc[r][2], acc[r][3]);
            *(float4*)(o + 4) = make_float4(acc[r][4], acc[r][5], acc[r][6], acc[r][7]);
        }
        float p1 = 0.0f, p2 = 0.0f;
#pragma unroll
        for (int c = 0; c < 8; ++c) {
            p1 = fmaf(acc[r][c], a1[c], p1);
            p2 = fmaf(acc[r][c], a2[c], p2);
        }
#pragma unroll
        for (int off = 8; off > 0; off >>= 1) {
            p1 += __shfl_xor(p1, off, 16);
            p2 += __shfl_xor(p2, off, 16);
        }
        if (valid && tx == 0) { s_src[grow] = p1; s_dst[grow] = p2; }
    }
}

// ---------------- K3: count in-degree per destination (real edges only) ----
__global__ __launch_bounds__(256) void k_count(const int* __restrict__ adj,
                                               int* __restrict__ cnt) {
    int e = blockIdx.x * blockDim.x + threadIdx.x;
    if (e >= N_EDGES) return;
    atomicAdd(&cnt[adj[N_EDGES + e]], 1);
}

// ---------------- K4: segment offsets (order-free exclusive scan) ----------
__global__ __launch_bounds__(256) void k_offsets(const int* __restrict__ cnt,
                                                 int* __restrict__ start,
                                                 int* __restrict__ fillptr,
                                                 int* total) {
    int i = blockIdx.x * blockDim.x + threadIdx.x;
    if (i >= N_NODES) return;
    int s = atomicAdd(total, cnt[i]);
    start[i] = s;
    fillptr[i] = s;
}

// ---------------- K5: fill CSR, compute exp(leakyrelu), accumulate denom ----
__global__ __launch_bounds__(256) void k_fill(const int* __restrict__ adj,
                                              const float* __restrict__ s_src,
                                              const float* __restrict__ s_dst,
                                              int* __restrict__ fillptr,
                                              float* __restrict__ denom,
                                              int* __restrict__ srcidx,
                                              float* __restrict__ exv) {
    int e = blockIdx.x * blockDim.x + threadIdx.x;
    if (e >= E_TOTAL) return;
    int row, col;
    if (e < N_EDGES) { row = adj[e]; col = adj[N_EDGES + e]; }
    else             { row = col = e - N_EDGES; }
    float s = s_dst[col] + s_src[row];
    float lr = (s > 0.0f) ? s : ALPHA * s;
    float ex = expf(lr);   // no max-shift needed: |s| << 88 by construction
    int pos = atomicAdd(&fillptr[col], 1);
    srcidx[pos] = row;
    exv[pos] = ex;
    atomicAdd(&denom[col], ex);
}

// ---------------- K6: gather, normalize, ELU ----------------
__global__ __launch_bounds__(256) void k_gather(const float* __restrict__ Wh,
                                                const int* __restrict__ start,
                                                const int* __restrict__ cnt,
                                                const int* __restrict__ srcidx,
                                                const float* __restrict__ exv,
                                                const float* __restrict__ denom,
                                                float* __restrict__ out) {
    int wave = (blockIdx.x * blockDim.x + threadIdx.x) >> 6;
    int lane = threadIdx.x & 63;
    if (wave >= N_NODES) return;
    int s0 = start[wave];
    int n  = cnt[wave];
    const float2* __restrict__ Wv = (const float2*)Wh;
    float2 acc = make_float2(0.0f, 0.0f);
    for (int j = 0; j < n; ++j) {
        int   r = srcidx[s0 + j];   // wave-uniform
        float x = exv[s0 + j];      // wave-uniform
        float2 w = Wv[(size_t)r * (OUT_F / 2) + lane];
        acc.x = fmaf(x, w.x, acc.x);
        acc.y = fmaf(x, w.y, acc.y);
    }
    float inv = 1.0f / denom[wave];
    float vx = acc.x * inv;
    float vy = acc.y * inv;
    vx = (vx > 0.0f) ? vx : expm1f(vx);
    vy = (vy > 0.0f) ? vy : expm1f(vy);
    ((float2*)(out + (size_t)wave * OUT_F))[lane] = make_float2(vx, vy);
}

// ---------------- launcher ----------------
extern "C" void kernel_launch(void* const* d_in, const int* in_sizes, int n_in,
                              void* d_out, int out_size, void* d_ws, size_t ws_size,
                              hipStream_t stream) {
    const float* h   = (const float*)d_in[0];
    const int*   adj = (const int*)d_in[1];
    const float* W   = (const float*)d_in[2];
    const float* a   = (const float*)d_in[3];
    float* out = (float*)d_out;

    // workspace layout (256B-aligned chunks)
    char* ws = (char*)d_ws;
    const size_t SZ_WH  = (size_t)N_NODES * OUT_F * 4;   // 25,600,000 (mult of 256)
    const size_t SZ_N   = 200704;                        // >= N_NODES*4, 256-aligned
    const size_t SZ_E   = 3400192;                       // >= E_TOTAL*4, 256-aligned
    float* Wh      = (float*)(ws);
    float* s_src   = (float*)(ws + SZ_WH);
    float* s_dst   = (float*)(ws + SZ_WH + SZ_N);
    float* denom   = (float*)(ws + SZ_WH + 2 * SZ_N);
    int*   cnt     = (int*)  (ws + SZ_WH + 3 * SZ_N);
    int*   start   = (int*)  (ws + SZ_WH + 4 * SZ_N);
    int*   fillptr = (int*)  (ws + SZ_WH + 5 * SZ_N);
    int*   total   = (int*)  (ws + SZ_WH + 6 * SZ_N);
    int*   srcidx  = (int*)  (ws + SZ_WH + 6 * SZ_N + 256);
    float* exv     = (float*)(ws + SZ_WH + 6 * SZ_N + 256 + SZ_E);

    (void)in_sizes; (void)n_in; (void)out_size; (void)ws_size;

    const int B = 256;
    k_init   <<<(N_NODES + B - 1) / B, B, 0, stream>>>(denom, cnt, total);
    k_gemm   <<<GEMM_BLOCKS, 128, 0, stream>>>(h, W, a, Wh, s_src, s_dst);
    k_count  <<<(N_EDGES + B - 1) / B, B, 0, stream>>>(adj, cnt);
    k_offsets<<<(N_NODES + B - 1) / B, B, 0, stream>>>(cnt, start, fillptr, total);
    k_fill   <<<(E_TOTAL + B - 1) / B, B, 0, stream>>>(adj, s_src, s_dst, fillptr,
                                                       denom, srcidx, exv);
    k_gather <<<(N_NODES * 64 + B - 1) / B, B, 0, stream>>>(Wh, start, cnt, srcidx,
                                                            exv, denom, out);
}

// Round 3
// 271.890 us; speedup vs baseline: 1.7410x; 1.3060x over previous
//
#include <hip/hip_runtime.h>
#include <math.h>

#define N_NODES 50000
#define N_EDGES 800000
#define E_TOTAL (N_NODES + N_EDGES)
#define IN_F 256
#define OUT_F 128
#define ALPHA 0.2f

#define TILE_M 64
#define BK 8
#define KTILES (IN_F / BK)          // 32
#define GEMM_BLOCKS ((N_NODES + TILE_M - 1) / TILE_M)   // 782

// f32 -> bf16 round-to-nearest-even (no NaN handling needed here)
static __device__ __forceinline__ unsigned short f2bf(float f) {
    unsigned int u = __float_as_uint(f);
    u += 0x7FFFu + ((u >> 16) & 1u);
    return (unsigned short)(u >> 16);
}
static __device__ __forceinline__ float bf2f(unsigned short u) {
    return __uint_as_float(((unsigned int)u) << 16);
}

// ---------------- K0: init counters ----------------
__global__ __launch_bounds__(256) void k_init(int* cnt, int* total) {
    int i = blockIdx.x * blockDim.x + threadIdx.x;
    if (i < N_NODES) cnt[i] = 1;   // 1 = implicit self-loop
    if (i == 0) *total = 0;
}

// ---------------- K1: Wh = h @ W  (LDS-tiled f32 GEMM) + fused scores -------
// 128 threads/block, 64 rows x 128 cols. Thread (tx=t&15, ty=t>>4) computes an
// 8x8 register tile. BK=8 k-slab staged in LDS; next slab register-prefetched.
// Epilogue: store Wh in bf16 (gather is the only consumer); fused
// s_src = Wh.a1, s_dst = Wh.a2 in f32 (width-16 shfl_xor reduction).
__global__ __launch_bounds__(128) void k_gemm(const float* __restrict__ h,
                                              const float* __restrict__ W,
                                              const float* __restrict__ a,
                                              unsigned short* __restrict__ Whb,
                                              float* __restrict__ s_src,
                                              float* __restrict__ s_dst) {
    __shared__ float hs[BK][TILE_M];       // k-major (transposed) h slab
    __shared__ float ws[BK][OUT_F + 4];    // +4 pad

    const int t = threadIdx.x;
    const int row0 = blockIdx.x * TILE_M;
    const int tx = t & 15, ty = t >> 4;

    const int lrow = t >> 1;               // 0..63 (h tile row)
    const int lk   = (t & 1) * 4;          // 0 or 4 (k sub-offset)
    int hrow = row0 + lrow; if (hrow >= N_NODES) hrow = N_NODES - 1;
    const float* __restrict__ hp = h + (size_t)hrow * IN_F + lk;
    const int wrow = t >> 4;               // 0..7 (k within slab)
    const int wcol = (t & 15) * 8;
    const float* __restrict__ wp = W + (size_t)wrow * OUT_F + wcol;

    float acc[8][8];
#pragma unroll
    for (int r = 0; r < 8; ++r)
#pragma unroll
        for (int c = 0; c < 8; ++c) acc[r][c] = 0.0f;

    {   // prologue: stage slab 0
        float4 hv  = *(const float4*)hp;
        float4 wv0 = *(const float4*)wp;
        float4 wv1 = *(const float4*)(wp + 4);
        hs[lk + 0][lrow] = hv.x; hs[lk + 1][lrow] = hv.y;
        hs[lk + 2][lrow] = hv.z; hs[lk + 3][lrow] = hv.w;
        *(float4*)&ws[wrow][wcol]     = wv0;
        *(float4*)&ws[wrow][wcol + 4] = wv1;
    }
    __syncthreads();

    for (int kt = 0; kt < KTILES; ++kt) {
        float4 nhv, nwv0, nwv1;
        const bool more = (kt + 1 < KTILES);
        if (more) {
            const float* hp2 = hp + (kt + 1) * BK;
            nhv = *(const float4*)hp2;
            const float* wp2 = wp + (size_t)(kt + 1) * BK * OUT_F;
            nwv0 = *(const float4*)wp2;
            nwv1 = *(const float4*)(wp2 + 4);
        }
#pragma unroll
        for (int kk = 0; kk < BK; ++kk) {
            float4 hA = *(const float4*)&hs[kk][ty * 8];
            float4 hB = *(const float4*)&hs[kk][ty * 8 + 4];
            float4 wA = *(const float4*)&ws[kk][tx * 8];
            float4 wB = *(const float4*)&ws[kk][tx * 8 + 4];
            float hr[8] = {hA.x, hA.y, hA.z, hA.w, hB.x, hB.y, hB.z, hB.w};
            float wc[8] = {wA.x, wA.y, wA.z, wA.w, wB.x, wB.y, wB.z, wB.w};
#pragma unroll
            for (int r = 0; r < 8; ++r)
#pragma unroll
                for (int c = 0; c < 8; ++c)
                    acc[r][c] = fmaf(hr[r], wc[c], acc[r][c]);
        }
        if (more) {
            __syncthreads();
            hs[lk + 0][lrow] = nhv.x; hs[lk + 1][lrow] = nhv.y;
            hs[lk + 2][lrow] = nhv.z; hs[lk + 3][lrow] = nhv.w;
            *(float4*)&ws[wrow][wcol]     = nwv0;
            *(float4*)&ws[wrow][wcol + 4] = nwv1;
            __syncthreads();
        }
    }

    // --- epilogue: bf16 Wh store + fused attention scores ---
    float a1[8], a2[8];
    *(float4*)&a1[0] = *(const float4*)(a + tx * 8);
    *(float4*)&a1[4] = *(const float4*)(a + tx * 8 + 4);
    *(float4*)&a2[0] = *(const float4*)(a + OUT_F + tx * 8);
    *(float4*)&a2[4] = *(const float4*)(a + OUT_F + tx * 8 + 4);

#pragma unroll
    for (int r = 0; r < 8; ++r) {
        const int grow = row0 + ty * 8 + r;
        const bool valid = (grow < N_NODES);
        if (valid) {
            uint4 pk;
            pk.x = (unsigned)f2bf(acc[r][0]) | ((unsigned)f2bf(acc[r][1]) << 16);
            pk.y = (unsigned)f2bf(acc[r][2]) | ((unsigned)f2bf(acc[r][3]) << 16);
            pk.z = (unsigned)f2bf(acc[r][4]) | ((unsigned)f2bf(acc[r][5]) << 16);
            pk.w = (unsigned)f2bf(acc[r][6]) | ((unsigned)f2bf(acc[r][7]) << 16);
            *(uint4*)(Whb + (size_t)grow * OUT_F + tx * 8) = pk;
        }
        float p1 = 0.0f, p2 = 0.0f;
#pragma unroll
        for (int c = 0; c < 8; ++c) {
            p1 = fmaf(acc[r][c], a1[c], p1);
            p2 = fmaf(acc[r][c], a2[c], p2);
        }
#pragma unroll
        for (int off = 8; off > 0; off >>= 1) {
            p1 += __shfl_xor(p1, off, 16);
            p2 += __shfl_xor(p2, off, 16);
        }
        if (valid && tx == 0) { s_src[grow] = p1; s_dst[grow] = p2; }
    }
}

// ---------------- K3: count in-degree per destination (real edges only) ----
__global__ __launch_bounds__(256) void k_count(const int* __restrict__ adj,
                                               int* __restrict__ cnt) {
    int e = blockIdx.x * blockDim.x + threadIdx.x;
    if (e >= N_EDGES) return;
    atomicAdd(&cnt[adj[N_EDGES + e]], 1);
}

// ---------------- K4: segment offsets (order-free exclusive scan) ----------
__global__ __launch_bounds__(256) void k_offsets(const int* __restrict__ cnt,
                                                 int* __restrict__ start,
                                                 int* __restrict__ fillptr,
                                                 int* total) {
    int i = blockIdx.x * blockDim.x + threadIdx.x;
    if (i >= N_NODES) return;
    int s = atomicAdd(total, cnt[i]);
    start[i] = s;
    fillptr[i] = s;
}

// ---------------- K5: fill CSR with packed (src, exp(leakyrelu)) ----------
__global__ __launch_bounds__(256) void k_fill(const int* __restrict__ adj,
                                              const float* __restrict__ s_src,
                                              const float* __restrict__ s_dst,
                                              int* __restrict__ fillptr,
                                              int2* __restrict__ pack) {
    int e = blockIdx.x * blockDim.x + threadIdx.x;
    if (e >= E_TOTAL) return;
    int row, col;
    if (e < N_EDGES) { row = adj[e]; col = adj[N_EDGES + e]; }
    else             { row = col = e - N_EDGES; }
    float s = s_dst[col] + s_src[row];
    float lr = (s > 0.0f) ? s : ALPHA * s;
    float ex = expf(lr);   // no max-shift needed: |s| << 88 by construction
    int pos = atomicAdd(&fillptr[col], 1);
    pack[pos] = make_int2(row, __float_as_int(ex));
}

// ---------------- K6: gather (bf16 Wh), normalize, ELU ----------------
// One wave per destination node; lane owns 2 consecutive features (ushort2).
// Edge loop unrolled x4 for 4 outstanding row-loads per wave. Softmax
// denominator accumulated in-loop (wave-uniform), no atomics.
__global__ __launch_bounds__(256) void k_gather(const unsigned short* __restrict__ Whb,
                                                const int* __restrict__ start,
                                                const int* __restrict__ cnt,
                                                const int2* __restrict__ pack,
                                                float* __restrict__ out) {
    int node = (blockIdx.x * blockDim.x + threadIdx.x) >> 6;
    int lane = threadIdx.x & 63;
    if (node >= N_NODES) return;
    int s0 = start[node];
    int n  = cnt[node];
    const uint* __restrict__ Wv = (const uint*)Whb;   // ushort2 as uint, [N][64]

    float ax = 0.0f, ay = 0.0f, dsum = 0.0f;
    int j = 0;
    for (; j + 4 <= n; j += 4) {
        int2 p0 = pack[s0 + j + 0];
        int2 p1 = pack[s0 + j + 1];
        int2 p2 = pack[s0 + j + 2];
        int2 p3 = pack[s0 + j + 3];
        uint w0 = Wv[(size_t)p0.x * (OUT_F / 2) + lane];
        uint w1 = Wv[(size_t)p1.x * (OUT_F / 2) + lane];
        uint w2 = Wv[(size_t)p2.x * (OUT_F / 2) + lane];
        uint w3 = Wv[(size_t)p3.x * (OUT_F / 2) + lane];
        float x0 = __int_as_float(p0.y), x1 = __int_as_float(p1.y);
        float x2 = __int_as_float(p2.y), x3 = __int_as_float(p3.y);
        ax = fmaf(x0, bf2f((unsigned short)(w0 & 0xFFFF)), ax);
        ay = fmaf(x0, bf2f((unsigned short)(w0 >> 16)), ay);
        ax = fmaf(x1, bf2f((unsigned short)(w1 & 0xFFFF)), ax);
        ay = fmaf(x1, bf2f((unsigned short)(w1 >> 16)), ay);
        ax = fmaf(x2, bf2f((unsigned short)(w2 & 0xFFFF)), ax);
        ay = fmaf(x2, bf2f((unsigned short)(w2 >> 16)), ay);
        ax = fmaf(x3, bf2f((unsigned short)(w3 & 0xFFFF)), ax);
        ay = fmaf(x3, bf2f((unsigned short)(w3 >> 16)), ay);
        dsum += (x0 + x1) + (x2 + x3);
    }
    for (; j < n; ++j) {
        int2 p = pack[s0 + j];
        uint w = Wv[(size_t)p.x * (OUT_F / 2) + lane];
        float x = __int_as_float(p.y);
        ax = fmaf(x, bf2f((unsigned short)(w & 0xFFFF)), ax);
        ay = fmaf(x, bf2f((unsigned short)(w >> 16)), ay);
        dsum += x;
    }
    float inv = 1.0f / dsum;
    float vx = ax * inv;
    float vy = ay * inv;
    vx = (vx > 0.0f) ? vx : expm1f(vx);
    vy = (vy > 0.0f) ? vy : expm1f(vy);
    ((float2*)(out + (size_t)node * OUT_F))[lane] = make_float2(vx, vy);
}

// ---------------- launcher ----------------
extern "C" void kernel_launch(void* const* d_in, const int* in_sizes, int n_in,
                              void* d_out, int out_size, void* d_ws, size_t ws_size,
                              hipStream_t stream) {
    const float* h   = (const float*)d_in[0];
    const int*   adj = (const int*)d_in[1];
    const float* W   = (const float*)d_in[2];
    const float* a   = (const float*)d_in[3];
    float* out = (float*)d_out;

    // workspace layout (256B-aligned chunks)
    char* ws = (char*)d_ws;
    const size_t SZ_WHB = (size_t)N_NODES * OUT_F * 2;   // 12,800,000 (mult of 256)
    const size_t SZ_N   = 200704;                        // >= N_NODES*4, 256-aligned
    unsigned short* Whb = (unsigned short*)(ws);
    float* s_src   = (float*)(ws + SZ_WHB);
    float* s_dst   = (float*)(ws + SZ_WHB + SZ_N);
    int*   cnt     = (int*)  (ws + SZ_WHB + 2 * SZ_N);
    int*   start   = (int*)  (ws + SZ_WHB + 3 * SZ_N);
    int*   fillptr = (int*)  (ws + SZ_WHB + 4 * SZ_N);
    int*   total   = (int*)  (ws + SZ_WHB + 5 * SZ_N);
    int2*  pack    = (int2*) (ws + SZ_WHB + 5 * SZ_N + 256);

    (void)in_sizes; (void)n_in; (void)out_size; (void)ws_size;

    const int B = 256;
    k_init   <<<(N_NODES + B - 1) / B, B, 0, stream>>>(cnt, total);
    k_gemm   <<<GEMM_BLOCKS, 128, 0, stream>>>(h, W, a, Whb, s_src, s_dst);
    k_count  <<<(N_EDGES + B - 1) / B, B, 0, stream>>>(adj, cnt);
    k_offsets<<<(N_NODES + B - 1) / B, B, 0, stream>>>(cnt, start, fillptr, total);
    k_fill   <<<(E_TOTAL + B - 1) / B, B, 0, stream>>>(adj, s_src, s_dst, fillptr, pack);
    k_gather <<<(N_NODES * 64 + B - 1) / B, B, 0, stream>>>(Whb, start, cnt, pack, out);
}

// Round 4
// 250.566 us; speedup vs baseline: 1.8891x; 1.0851x over previous
//
#include <hip/hip_runtime.h>
#include <math.h>

#define N_NODES 50000
#define N_EDGES 800000
#define E_TOTAL (N_NODES + N_EDGES)
#define IN_F 256
#define OUT_F 128
#define ALPHA 0.2f

#define GEMM_WAVES ((N_NODES + 31) / 32)              // 1563 (32 rows/wave)
#define GEMM_BLOCKS ((GEMM_WAVES + 3) / 4)            // 391

typedef short bf16x8 __attribute__((ext_vector_type(8)));
typedef float f32x4  __attribute__((ext_vector_type(4)));

// f32 -> bf16 round-to-nearest-even (no NaN handling needed here)
static __device__ __forceinline__ unsigned short f2bf(float f) {
    unsigned int u = __float_as_uint(f);
    u += 0x7FFFu + ((u >> 16) & 1u);
    return (unsigned short)(u >> 16);
}
static __device__ __forceinline__ float bf2f(unsigned short u) {
    return __uint_as_float(((unsigned int)u) << 16);
}

// ---------------- K0: init counters ----------------
__global__ __launch_bounds__(256) void k_init(int* cnt, int* total) {
    int i = blockIdx.x * blockDim.x + threadIdx.x;
    if (i < N_NODES) cnt[i] = 1;   // 1 = implicit self-loop
    if (i == 0) *total = 0;
}

// ---------------- P1: Wa1 = W @ a[:128], Wa2 = W @ a[128:]  (f32 exact) ----
// 1 block x 256 threads; thread k does a 128-dot against both halves of a.
__global__ __launch_bounds__(256) void k_prep_wa(const float* __restrict__ W,
                                                 const float* __restrict__ a,
                                                 float* __restrict__ Wa) {
    int k = threadIdx.x;
    const float4* wr  = (const float4*)(W + (size_t)k * OUT_F);
    const float4* av1 = (const float4*)a;
    const float4* av2 = (const float4*)(a + OUT_F);
    float s1 = 0.0f, s2 = 0.0f;
#pragma unroll 8
    for (int i = 0; i < OUT_F / 4; ++i) {
        float4 w = wr[i], x = av1[i], y = av2[i];
        s1 = fmaf(w.x, x.x, fmaf(w.y, x.y, fmaf(w.z, x.z, fmaf(w.w, x.w, s1))));
        s2 = fmaf(w.x, y.x, fmaf(w.y, y.y, fmaf(w.z, y.z, fmaf(w.w, y.w, s2))));
    }
    Wa[k] = s1;
    Wa[IN_F + k] = s2;
}

// ---------------- P2: WbT[n][k] = bf16(W[k][n])  (B-operand layout) --------
// grid 128 blocks (n), 256 threads (k): coalesced 2B writes.
__global__ __launch_bounds__(256) void k_prep_wt(const float* __restrict__ W,
                                                 unsigned short* __restrict__ WbT) {
    int n = blockIdx.x;
    int k = threadIdx.x;
    WbT[(size_t)n * IN_F + k] = f2bf(W[(size_t)k * OUT_F + n]);
}

// ---------------- K1: Wh = h @ W via bf16 MFMA + fused f32 scores ----------
// One wave = 32 rows x 128 cols = 2 row-tiles x 8 col-tiles of 16x16x32 MFMA.
// No LDS: h frags loaded direct (128B-line coalesced, f32->bf16 cvt);
// W^T frags loaded direct from 64KB WbT (L1/L2 resident).
// Operands: mfma(wfrag, hfrag, acc) -> C col = h-row (lane&15),
// C row = out-feature (grp*4+reg) -> contiguous ushort4 stores.
// Scores use the PRE-conversion f32 h values against f32 Wa (exact).
__global__ __launch_bounds__(256) void k_gemm(const float* __restrict__ h,
                                              const unsigned short* __restrict__ WbT,
                                              const float* __restrict__ Wa,
                                              unsigned short* __restrict__ Whb,
                                              float* __restrict__ s_src,
                                              float* __restrict__ s_dst) {
    const int wid  = (blockIdx.x * blockDim.x + threadIdx.x) >> 6;
    const int lane = threadIdx.x & 63;
    if (wid >= GEMM_WAVES) return;
    const int m = lane & 15, grp = lane >> 4;
    const int row0 = wid * 32;

    f32x4 acc[2][8];
#pragma unroll
    for (int rt = 0; rt < 2; ++rt)
#pragma unroll
        for (int nt = 0; nt < 8; ++nt) acc[rt][nt] = (f32x4){0.f, 0.f, 0.f, 0.f};
    float sp1[2] = {0.f, 0.f}, sp2[2] = {0.f, 0.f};

    for (int kt = 0; kt < 8; ++kt) {
        const int k0 = kt * 32;
        // --- load + convert h fragments; accumulate f32 score partials ---
        bf16x8 hfrag[2];
#pragma unroll
        for (int rt = 0; rt < 2; ++rt) {
            int r = row0 + rt * 16 + m;
            if (r >= N_NODES) r = N_NODES - 1;   // clamp; stores guarded
            const float4* hp = (const float4*)(h + (size_t)r * IN_F + k0 + grp * 8);
            float4 x0 = hp[0], x1 = hp[1];
            const float4* wap1 = (const float4*)(Wa + k0 + grp * 8);
            const float4* wap2 = (const float4*)(Wa + IN_F + k0 + grp * 8);
            float4 a0 = wap1[0], a1 = wap1[1];
            float4 b0 = wap2[0], b1 = wap2[1];
            sp1[rt] = fmaf(x0.x, a0.x, fmaf(x0.y, a0.y, fmaf(x0.z, a0.z, fmaf(x0.w, a0.w, sp1[rt]))));
            sp1[rt] = fmaf(x1.x, a1.x, fmaf(x1.y, a1.y, fmaf(x1.z, a1.z, fmaf(x1.w, a1.w, sp1[rt]))));
            sp2[rt] = fmaf(x0.x, b0.x, fmaf(x0.y, b0.y, fmaf(x0.z, b0.z, fmaf(x0.w, b0.w, sp2[rt]))));
            sp2[rt] = fmaf(x1.x, b1.x, fmaf(x1.y, b1.y, fmaf(x1.z, b1.z, fmaf(x1.w, b1.w, sp2[rt]))));
            bf16x8 hf;
            hf[0] = (short)f2bf(x0.x); hf[1] = (short)f2bf(x0.y);
            hf[2] = (short)f2bf(x0.z); hf[3] = (short)f2bf(x0.w);
            hf[4] = (short)f2bf(x1.x); hf[5] = (short)f2bf(x1.y);
            hf[6] = (short)f2bf(x1.z); hf[7] = (short)f2bf(x1.w);
            hfrag[rt] = hf;
        }
        // --- 8 col-tiles: load W^T fragment, 2 MFMAs each ---
#pragma unroll
        for (int nt = 0; nt < 8; ++nt) {
            bf16x8 wf = *(const bf16x8*)(WbT + (size_t)(nt * 16 + m) * IN_F + k0 + grp * 8);
            acc[0][nt] = __builtin_amdgcn_mfma_f32_16x16x32_bf16(wf, hfrag[0], acc[0][nt], 0, 0, 0);
            acc[1][nt] = __builtin_amdgcn_mfma_f32_16x16x32_bf16(wf, hfrag[1], acc[1][nt], 0, 0, 0);
        }
    }

    // --- epilogue: scores (shfl reduce over grp) + bf16 Wh stores ---
#pragma unroll
    for (int rt = 0; rt < 2; ++rt) {
        const int row = row0 + rt * 16 + m;
        const bool valid = (row < N_NODES);
        float t1 = sp1[rt], t2 = sp2[rt];
        t1 += __shfl_xor(t1, 16); t1 += __shfl_xor(t1, 32);
        t2 += __shfl_xor(t2, 16); t2 += __shfl_xor(t2, 32);
        if (valid && grp == 0) { s_src[row] = t1; s_dst[row] = t2; }
        if (valid) {
            unsigned short* orow = Whb + (size_t)row * OUT_F;
#pragma unroll
            for (int nt = 0; nt < 8; ++nt) {
                f32x4 v = acc[rt][nt];
                ushort4 pk;
                pk.x = f2bf(v[0]); pk.y = f2bf(v[1]);
                pk.z = f2bf(v[2]); pk.w = f2bf(v[3]);
                *(ushort4*)(orow + nt * 16 + grp * 4) = pk;
            }
        }
    }
}

// ---------------- K3: count in-degree per destination (real edges only) ----
__global__ __launch_bounds__(256) void k_count(const int* __restrict__ adj,
                                               int* __restrict__ cnt) {
    int e = blockIdx.x * blockDim.x + threadIdx.x;
    if (e >= N_EDGES) return;
    atomicAdd(&cnt[adj[N_EDGES + e]], 1);
}

// ---------------- K4: segment offsets (order-free exclusive scan) ----------
__global__ __launch_bounds__(256) void k_offsets(const int* __restrict__ cnt,
                                                 int* __restrict__ start,
                                                 int* __restrict__ fillptr,
                                                 int* total) {
    int i = blockIdx.x * blockDim.x + threadIdx.x;
    if (i >= N_NODES) return;
    int s = atomicAdd(total, cnt[i]);
    start[i] = s;
    fillptr[i] = s;
}

// ---------------- K5: fill CSR with packed (src, exp(leakyrelu)) ----------
__global__ __launch_bounds__(256) void k_fill(const int* __restrict__ adj,
                                              const float* __restrict__ s_src,
                                              const float* __restrict__ s_dst,
                                              int* __restrict__ fillptr,
                                              int2* __restrict__ pack) {
    int e = blockIdx.x * blockDim.x + threadIdx.x;
    if (e >= E_TOTAL) return;
    int row, col;
    if (e < N_EDGES) { row = adj[e]; col = adj[N_EDGES + e]; }
    else             { row = col = e - N_EDGES; }
    float s = s_dst[col] + s_src[row];
    float lr = (s > 0.0f) ? s : ALPHA * s;
    float ex = expf(lr);   // no max-shift needed: |s| << 88 by construction
    int pos = atomicAdd(&fillptr[col], 1);
    pack[pos] = make_int2(row, __float_as_int(ex));
}

// ---------------- K6: gather (bf16 Wh), normalize, ELU ----------------
// One wave per destination node; lane owns 2 consecutive features (ushort2).
// Edge loop unrolled x4 for 4 outstanding row-loads per wave. Softmax
// denominator accumulated in-loop (wave-uniform), no atomics.
__global__ __launch_bounds__(256) void k_gather(const unsigned short* __restrict__ Whb,
                                                const int* __restrict__ start,
                                                const int* __restrict__ cnt,
                                                const int2* __restrict__ pack,
                                                float* __restrict__ out) {
    int node = (blockIdx.x * blockDim.x + threadIdx.x) >> 6;
    int lane = threadIdx.x & 63;
    if (node >= N_NODES) return;
    int s0 = start[node];
    int n  = cnt[node];
    const uint* __restrict__ Wv = (const uint*)Whb;   // ushort2 as uint, [N][64]

    float ax = 0.0f, ay = 0.0f, dsum = 0.0f;
    int j = 0;
    for (; j + 4 <= n; j += 4) {
        int2 p0 = pack[s0 + j + 0];
        int2 p1 = pack[s0 + j + 1];
        int2 p2 = pack[s0 + j + 2];
        int2 p3 = pack[s0 + j + 3];
        uint w0 = Wv[(size_t)p0.x * (OUT_F / 2) + lane];
        uint w1 = Wv[(size_t)p1.x * (OUT_F / 2) + lane];
        uint w2 = Wv[(size_t)p2.x * (OUT_F / 2) + lane];
        uint w3 = Wv[(size_t)p3.x * (OUT_F / 2) + lane];
        float x0 = __int_as_float(p0.y), x1 = __int_as_float(p1.y);
        float x2 = __int_as_float(p2.y), x3 = __int_as_float(p3.y);
        ax = fmaf(x0, bf2f((unsigned short)(w0 & 0xFFFF)), ax);
        ay = fmaf(x0, bf2f((unsigned short)(w0 >> 16)), ay);
        ax = fmaf(x1, bf2f((unsigned short)(w1 & 0xFFFF)), ax);
        ay = fmaf(x1, bf2f((unsigned short)(w1 >> 16)), ay);
        ax = fmaf(x2, bf2f((unsigned short)(w2 & 0xFFFF)), ax);
        ay = fmaf(x2, bf2f((unsigned short)(w2 >> 16)), ay);
        ax = fmaf(x3, bf2f((unsigned short)(w3 & 0xFFFF)), ax);
        ay = fmaf(x3, bf2f((unsigned short)(w3 >> 16)), ay);
        dsum += (x0 + x1) + (x2 + x3);
    }
    for (; j < n; ++j) {
        int2 p = pack[s0 + j];
        uint w = Wv[(size_t)p.x * (OUT_F / 2) + lane];
        float x = __int_as_float(p.y);
        ax = fmaf(x, bf2f((unsigned short)(w & 0xFFFF)), ax);
        ay = fmaf(x, bf2f((unsigned short)(w >> 16)), ay);
        dsum += x;
    }
    float inv = 1.0f / dsum;
    float vx = ax * inv;
    float vy = ay * inv;
    vx = (vx > 0.0f) ? vx : expm1f(vx);
    vy = (vy > 0.0f) ? vy : expm1f(vy);
    ((float2*)(out + (size_t)node * OUT_F))[lane] = make_float2(vx, vy);
}

// ---------------- launcher ----------------
extern "C" void kernel_launch(void* const* d_in, const int* in_sizes, int n_in,
                              void* d_out, int out_size, void* d_ws, size_t ws_size,
                              hipStream_t stream) {
    const float* h   = (const float*)d_in[0];
    const int*   adj = (const int*)d_in[1];
    const float* W   = (const float*)d_in[2];
    const float* a   = (const float*)d_in[3];
    float* out = (float*)d_out;

    // workspace layout (256B-aligned chunks)
    char* ws = (char*)d_ws;
    const size_t SZ_WHB = (size_t)N_NODES * OUT_F * 2;   // 12,800,000 (mult of 256)
    const size_t SZ_N   = 200704;                        // >= N_NODES*4, 256-aligned
    unsigned short* Whb = (unsigned short*)(ws);
    float* s_src   = (float*)(ws + SZ_WHB);
    float* s_dst   = (float*)(ws + SZ_WHB + SZ_N);
    int*   cnt     = (int*)  (ws + SZ_WHB + 2 * SZ_N);
    int*   start   = (int*)  (ws + SZ_WHB + 3 * SZ_N);
    int*   fillptr = (int*)  (ws + SZ_WHB + 4 * SZ_N);
    int*   total   = (int*)  (ws + SZ_WHB + 5 * SZ_N);
    float* Wa      = (float*)(ws + SZ_WHB + 5 * SZ_N + 256);            // 2KB
    unsigned short* WbT = (unsigned short*)(ws + SZ_WHB + 5 * SZ_N + 256 + 2048); // 64KB
    int2*  pack    = (int2*) (ws + SZ_WHB + 5 * SZ_N + 256 + 2048 + 65536);

    (void)in_sizes; (void)n_in; (void)out_size; (void)ws_size;

    const int B = 256;
    k_init   <<<(N_NODES + B - 1) / B, B, 0, stream>>>(cnt, total);
    k_prep_wa<<<1, 256, 0, stream>>>(W, a, Wa);
    k_prep_wt<<<OUT_F, 256, 0, stream>>>(W, WbT);
    k_gemm   <<<GEMM_BLOCKS, 256, 0, stream>>>(h, WbT, Wa, Whb, s_src, s_dst);
    k_count  <<<(N_EDGES + B - 1) / B, B, 0, stream>>>(adj, cnt);
    k_offsets<<<(N_NODES + B - 1) / B, B, 0, stream>>>(cnt, start, fillptr, total);
    k_fill   <<<(E_TOTAL + B - 1) / B, B, 0, stream>>>(adj, s_src, s_dst, fillptr, pack);
    k_gather <<<(N_NODES * 64 + B - 1) / B, B, 0, stream>>>(Whb, start, cnt, pack, out);
}

// Round 5
// 222.087 us; speedup vs baseline: 2.1314x; 1.1282x over previous
//
#include <hip/hip_runtime.h>
#include <math.h>

#define N_NODES 50000
#define N_EDGES 800000
#define E_TOTAL (N_NODES + N_EDGES)
#define IN_F 256
#define OUT_F 128
#define ALPHA 0.2f

#define GEMM_WAVES ((N_NODES + 31) / 32)              // 1563 (32 rows/wave)
#define GEMM_BLOCKS ((GEMM_WAVES + 3) / 4)            // 391

typedef short bf16x8 __attribute__((ext_vector_type(8)));
typedef float f32x4  __attribute__((ext_vector_type(4)));

// f32 -> bf16 round-to-nearest-even (no NaN handling needed here)
static __device__ __forceinline__ unsigned short f2bf(float f) {
    unsigned int u = __float_as_uint(f);
    u += 0x7FFFu + ((u >> 16) & 1u);
    return (unsigned short)(u >> 16);
}
static __device__ __forceinline__ float bf2f(unsigned int u16) {
    return __uint_as_float(u16 << 16);
}

// ---------------- K0: init list heads ----------------
__global__ __launch_bounds__(256) void k_init(int* head) {
    int i = blockIdx.x * blockDim.x + threadIdx.x;
    if (i < N_NODES) head[i] = -1;
}

// ---------------- P1: Wa1 = W @ a[:128], Wa2 = W @ a[128:]  (f32 exact) ----
__global__ __launch_bounds__(256) void k_prep_wa(const float* __restrict__ W,
                                                 const float* __restrict__ a,
                                                 float* __restrict__ Wa) {
    int k = threadIdx.x;
    const float4* wr  = (const float4*)(W + (size_t)k * OUT_F);
    const float4* av1 = (const float4*)a;
    const float4* av2 = (const float4*)(a + OUT_F);
    float s1 = 0.0f, s2 = 0.0f;
#pragma unroll 8
    for (int i = 0; i < OUT_F / 4; ++i) {
        float4 w = wr[i], x = av1[i], y = av2[i];
        s1 = fmaf(w.x, x.x, fmaf(w.y, x.y, fmaf(w.z, x.z, fmaf(w.w, x.w, s1))));
        s2 = fmaf(w.x, y.x, fmaf(w.y, y.y, fmaf(w.z, y.z, fmaf(w.w, y.w, s2))));
    }
    Wa[k] = s1;
    Wa[IN_F + k] = s2;
}

// ---------------- P2: WbT[n][k] = bf16(W[k][n])  (B-operand layout) --------
__global__ __launch_bounds__(256) void k_prep_wt(const float* __restrict__ W,
                                                 unsigned short* __restrict__ WbT) {
    int n = blockIdx.x;
    int k = threadIdx.x;
    WbT[(size_t)n * IN_F + k] = f2bf(W[(size_t)k * OUT_F + n]);
}

// ---------------- K1: Wh = h @ W via bf16 MFMA + fused f32 scores ----------
// One wave = 32 rows x 128 cols = 2 row-tiles x 8 col-tiles of 16x16x32 MFMA.
// No LDS. Scores use PRE-conversion f32 h against f32 Wa (exact).
__global__ __launch_bounds__(256) void k_gemm(const float* __restrict__ h,
                                              const unsigned short* __restrict__ WbT,
                                              const float* __restrict__ Wa,
                                              unsigned short* __restrict__ Whb,
                                              float* __restrict__ s_src,
                                              float* __restrict__ s_dst) {
    const int wid  = (blockIdx.x * blockDim.x + threadIdx.x) >> 6;
    const int lane = threadIdx.x & 63;
    if (wid >= GEMM_WAVES) return;
    const int m = lane & 15, grp = lane >> 4;
    const int row0 = wid * 32;

    f32x4 acc[2][8];
#pragma unroll
    for (int rt = 0; rt < 2; ++rt)
#pragma unroll
        for (int nt = 0; nt < 8; ++nt) acc[rt][nt] = (f32x4){0.f, 0.f, 0.f, 0.f};
    float sp1[2] = {0.f, 0.f}, sp2[2] = {0.f, 0.f};

    for (int kt = 0; kt < 8; ++kt) {
        const int k0 = kt * 32;
        bf16x8 hfrag[2];
#pragma unroll
        for (int rt = 0; rt < 2; ++rt) {
            int r = row0 + rt * 16 + m;
            if (r >= N_NODES) r = N_NODES - 1;   // clamp; stores guarded
            const float4* hp = (const float4*)(h + (size_t)r * IN_F + k0 + grp * 8);
            float4 x0 = hp[0], x1 = hp[1];
            const float4* wap1 = (const float4*)(Wa + k0 + grp * 8);
            const float4* wap2 = (const float4*)(Wa + IN_F + k0 + grp * 8);
            float4 a0 = wap1[0], a1 = wap1[1];
            float4 b0 = wap2[0], b1 = wap2[1];
            sp1[rt] = fmaf(x0.x, a0.x, fmaf(x0.y, a0.y, fmaf(x0.z, a0.z, fmaf(x0.w, a0.w, sp1[rt]))));
            sp1[rt] = fmaf(x1.x, a1.x, fmaf(x1.y, a1.y, fmaf(x1.z, a1.z, fmaf(x1.w, a1.w, sp1[rt]))));
            sp2[rt] = fmaf(x0.x, b0.x, fmaf(x0.y, b0.y, fmaf(x0.z, b0.z, fmaf(x0.w, b0.w, sp2[rt]))));
            sp2[rt] = fmaf(x1.x, b1.x, fmaf(x1.y, b1.y, fmaf(x1.z, b1.z, fmaf(x1.w, b1.w, sp2[rt]))));
            bf16x8 hf;
            hf[0] = (short)f2bf(x0.x); hf[1] = (short)f2bf(x0.y);
            hf[2] = (short)f2bf(x0.z); hf[3] = (short)f2bf(x0.w);
            hf[4] = (short)f2bf(x1.x); hf[5] = (short)f2bf(x1.y);
            hf[6] = (short)f2bf(x1.z); hf[7] = (short)f2bf(x1.w);
            hfrag[rt] = hf;
        }
#pragma unroll
        for (int nt = 0; nt < 8; ++nt) {
            bf16x8 wf = *(const bf16x8*)(WbT + (size_t)(nt * 16 + m) * IN_F + k0 + grp * 8);
            acc[0][nt] = __builtin_amdgcn_mfma_f32_16x16x32_bf16(wf, hfrag[0], acc[0][nt], 0, 0, 0);
            acc[1][nt] = __builtin_amdgcn_mfma_f32_16x16x32_bf16(wf, hfrag[1], acc[1][nt], 0, 0, 0);
        }
    }

#pragma unroll
    for (int rt = 0; rt < 2; ++rt) {
        const int row = row0 + rt * 16 + m;
        const bool valid = (row < N_NODES);
        float t1 = sp1[rt], t2 = sp2[rt];
        t1 += __shfl_xor(t1, 16); t1 += __shfl_xor(t1, 32);
        t2 += __shfl_xor(t2, 16); t2 += __shfl_xor(t2, 32);
        if (valid && grp == 0) { s_src[row] = t1; s_dst[row] = t2; }
        if (valid) {
            unsigned short* orow = Whb + (size_t)row * OUT_F;
#pragma unroll
            for (int nt = 0; nt < 8; ++nt) {
                f32x4 v = acc[rt][nt];
                ushort4 pk;
                pk.x = f2bf(v[0]); pk.y = f2bf(v[1]);
                pk.z = f2bf(v[2]); pk.w = f2bf(v[3]);
                *(ushort4*)(orow + nt * 16 + grp * 4) = pk;
            }
        }
    }
}

// ---------------- K2: build per-destination linked lists ----------------
// Only random access is a 4B atomicExch into the 200KB head array (L2).
// list[e] = {src, next} is written COALESCED by edge id.
__global__ __launch_bounds__(256) void k_link(const int* __restrict__ adj,
                                              int* __restrict__ head,
                                              int2* __restrict__ list) {
    int e = blockIdx.x * blockDim.x + threadIdx.x;
    if (e >= N_EDGES) return;
    int src = adj[e];
    int col = adj[N_EDGES + e];
    int old = atomicExch(&head[col], e);
    list[e] = make_int2(src, old);
}

// ---------------- K3: gather via list walk, softmax, ELU ----------------
// 2 nodes per wave (half-wave = 32 lanes x 4 features, uint2 bf16 loads)
// -> 2 independent pointer chases per wave. Self-loop folded in at init.
// exp(leakyrelu(...)) recomputed from L2-resident s_src/s_dst (no exv array).
__global__ __launch_bounds__(256) void k_gather(const unsigned short* __restrict__ Whb,
                                                const int* __restrict__ head,
                                                const int2* __restrict__ list,
                                                const float* __restrict__ s_src,
                                                const float* __restrict__ s_dst,
                                                float* __restrict__ out) {
    int wid  = (blockIdx.x * blockDim.x + threadIdx.x) >> 6;
    int tl   = threadIdx.x & 63;
    int half = tl >> 5;
    int l    = tl & 31;
    int node = wid * 2 + half;
    if (node >= N_NODES) return;

    float sd = s_dst[node];

    // self-loop contribution (row == col == node)
    float s0 = sd + s_src[node];
    float lr0 = (s0 > 0.0f) ? s0 : ALPHA * s0;
    float x0 = __expf(lr0);
    uint2 w0 = *((const uint2*)(Whb + (size_t)node * OUT_F) + l);
    float4 acc;
    acc.x = x0 * bf2f(w0.x & 0xFFFFu);
    acc.y = x0 * bf2f(w0.x >> 16);
    acc.z = x0 * bf2f(w0.y & 0xFFFFu);
    acc.w = x0 * bf2f(w0.y >> 16);
    float dsum = x0;

    int e = head[node];
    while (e >= 0) {
        int2 rec = list[e];          // {src, next} -- the chase chain
        e = rec.y;                   // advance chain ASAP (next list load can issue)
        float ss = s_src[rec.x];
        uint2 wv = *((const uint2*)(Whb + (size_t)rec.x * OUT_F) + l);
        float s = sd + ss;
        float lr = (s > 0.0f) ? s : ALPHA * s;
        float x = __expf(lr);
        acc.x = fmaf(x, bf2f(wv.x & 0xFFFFu), acc.x);
        acc.y = fmaf(x, bf2f(wv.x >> 16), acc.y);
        acc.z = fmaf(x, bf2f(wv.y & 0xFFFFu), acc.z);
        acc.w = fmaf(x, bf2f(wv.y >> 16), acc.w);
        dsum += x;
    }

    float inv = 1.0f / dsum;
    float4 v;
    v.x = acc.x * inv; v.y = acc.y * inv;
    v.z = acc.z * inv; v.w = acc.w * inv;
    v.x = (v.x > 0.0f) ? v.x : expm1f(v.x);
    v.y = (v.y > 0.0f) ? v.y : expm1f(v.y);
    v.z = (v.z > 0.0f) ? v.z : expm1f(v.z);
    v.w = (v.w > 0.0f) ? v.w : expm1f(v.w);
    *((float4*)(out + (size_t)node * OUT_F) + l) = v;
}

// ---------------- launcher ----------------
extern "C" void kernel_launch(void* const* d_in, const int* in_sizes, int n_in,
                              void* d_out, int out_size, void* d_ws, size_t ws_size,
                              hipStream_t stream) {
    const float* h   = (const float*)d_in[0];
    const int*   adj = (const int*)d_in[1];
    const float* W   = (const float*)d_in[2];
    const float* a   = (const float*)d_in[3];
    float* out = (float*)d_out;

    // workspace layout (256B-aligned chunks)
    char* ws = (char*)d_ws;
    const size_t SZ_WHB = (size_t)N_NODES * OUT_F * 2;   // 12,800,000 (mult of 256)
    const size_t SZ_N   = 200704;                        // >= N_NODES*4, 256-aligned
    unsigned short* Whb = (unsigned short*)(ws);
    float* s_src   = (float*)(ws + SZ_WHB);
    float* s_dst   = (float*)(ws + SZ_WHB + SZ_N);
    int*   head    = (int*)  (ws + SZ_WHB + 2 * SZ_N);
    float* Wa      = (float*)(ws + SZ_WHB + 3 * SZ_N);                  // 2KB
    unsigned short* WbT = (unsigned short*)(ws + SZ_WHB + 3 * SZ_N + 2048);  // 64KB
    int2*  list    = (int2*) (ws + SZ_WHB + 3 * SZ_N + 2048 + 65536);   // 6.4MB

    (void)in_sizes; (void)n_in; (void)out_size; (void)ws_size;

    const int B = 256;
    k_init   <<<(N_NODES + B - 1) / B, B, 0, stream>>>(head);
    k_prep_wa<<<1, 256, 0, stream>>>(W, a, Wa);
    k_prep_wt<<<OUT_F, 256, 0, stream>>>(W, WbT);
    k_gemm   <<<GEMM_BLOCKS, 256, 0, stream>>>(h, WbT, Wa, Whb, s_src, s_dst);
    k_link   <<<(N_EDGES + B - 1) / B, B, 0, stream>>>(adj, head, list);
    k_gather <<<((N_NODES + 1) / 2 * 64 + B - 1) / B, B, 0, stream>>>(Whb, head, list,
                                                                      s_src, s_dst, out);
}